// Round 2
// baseline (166.261 us; speedup 1.0000x reference)
//
#include <hip/hip_runtime.h>
#include <hip/hip_bf16.h>

#define NB 4
#define NH 8
#define NPX 1024
#define HD 64
#define CDIM 512
#define M_ROWS 4096
#define PS 64
#define S2 16

typedef __attribute__((ext_vector_type(8))) short bf16x8;
typedef __attribute__((ext_vector_type(4))) short bf16x4;
typedef __attribute__((ext_vector_type(4))) float f32x4;

typedef const __attribute__((address_space(1))) unsigned int* gptr_t;
typedef __attribute__((address_space(3))) unsigned int* lptr_t;

static __device__ __forceinline__ short f2bf(float f) {
    __hip_bfloat16 h = __float2bfloat16(f);
    return *reinterpret_cast<short*>(&h);
}

// ---------------- convert: fp32 -> bf16 (x_l, x_s) and transposed bf16 weights ----------------
__global__ void convert_k(const float* __restrict__ xs, const float* __restrict__ xl,
                          const float* __restrict__ Wq, const float* __restrict__ Wk,
                          const float* __restrict__ Wv,
                          short* __restrict__ xl_bf, short* __restrict__ xs_bf,
                          short* __restrict__ WT /* [3][512*512], row=n col=k */) {
    int i = blockIdx.x * blockDim.x + threadIdx.x;   // 0 .. 786431
    if (i < 524288) {
        float4 a = ((const float4*)xl)[i];
        float4 b = ((const float4*)xs)[i];
        short4 oa = make_short4(f2bf(a.x), f2bf(a.y), f2bf(a.z), f2bf(a.w));
        short4 ob = make_short4(f2bf(b.x), f2bf(b.y), f2bf(b.z), f2bf(b.w));
        ((short4*)xl_bf)[i] = oa;
        ((short4*)xs_bf)[i] = ob;
    }
    if (i < 786432) {
        int which = i >> 18;
        int j = i & 262143;
        int n = j >> 9, k = j & 511;
        const float* W = which == 0 ? Wq : (which == 1 ? Wk : Wv);
        WT[i] = f2bf(W[k * 512 + n]);
    }
}

// ---------------- projection GEMM: out[z] = A[z] @ W[z] + b[z], bf16 out ----------------
// z=0: q = x_l@Wq+bq ; z=1: k = x_s@Wk+bk ; z=2: v = x_s@Wv+bv
// A row-major [4096][512] bf16, WT row-major [512 n][512 k] bf16, out [4096][512] bf16.
__global__ __launch_bounds__(256, 2) void proj_gemm(
    const short* __restrict__ xl_bf, const short* __restrict__ xs_bf,
    const short* __restrict__ WT, const float* __restrict__ bq,
    const float* __restrict__ bk, const float* __restrict__ bv,
    short* __restrict__ qkv) {
    __shared__ __attribute__((aligned(16))) short A_lds[128 * 32];
    __shared__ __attribute__((aligned(16))) short B_lds[64 * 32];
    const int z = blockIdx.z;
    const int m0 = blockIdx.x * 128;
    const int n0 = blockIdx.y * 64;
    const short* A = (z == 0) ? xl_bf : xs_bf;
    const short* WTz = WT + z * 262144;
    const float* bias = (z == 0) ? bq : ((z == 1) ? bk : bv);
    short* out = qkv + (size_t)z * M_ROWS * CDIM;
    const int t = threadIdx.x, w = t >> 6, lane = t & 63;
    const int lr = lane & 15, g = lane >> 4;

    f32x4 acc[2][4] = {};
    for (int kt = 0; kt < 16; ++kt) {
        const int k0 = kt * 32;
        // stage A tile [128][32] : 512 chunks of 16B, 2 rounds
#pragma unroll
        for (int r = 0; r < 2; ++r) {
            int c = r * 256 + w * 64 + lane;
            const short* src = A + (size_t)(m0 + (c >> 2)) * CDIM + k0 + (c & 3) * 8;
            __builtin_amdgcn_global_load_lds((gptr_t)src,
                (lptr_t)(A_lds + (size_t)(r * 256 + w * 64) * 8), 16, 0, 0);
        }
        // stage B^T tile [64][32] : 256 chunks
        {
            int c = w * 64 + lane;
            const short* src = WTz + (size_t)(n0 + (c >> 2)) * CDIM + k0 + (c & 3) * 8;
            __builtin_amdgcn_global_load_lds((gptr_t)src,
                (lptr_t)(B_lds + (size_t)(w * 64) * 8), 16, 0, 0);
        }
        __syncthreads();
        bf16x8 afr[2], bfr[4];
#pragma unroll
        for (int mt = 0; mt < 2; ++mt)
            afr[mt] = *(const bf16x8*)(A_lds + (w * 32 + mt * 16 + lr) * 32 + g * 8);
#pragma unroll
        for (int nt = 0; nt < 4; ++nt)
            bfr[nt] = *(const bf16x8*)(B_lds + (nt * 16 + lr) * 32 + g * 8);
#pragma unroll
        for (int mt = 0; mt < 2; ++mt)
#pragma unroll
            for (int nt = 0; nt < 4; ++nt)
                acc[mt][nt] = __builtin_amdgcn_mfma_f32_16x16x32_bf16(
                    afr[mt], bfr[nt], acc[mt][nt], 0, 0, 0);
        __syncthreads();
    }
    // epilogue: + bias, -> bf16.  C layout: col=lane&15, row=4*(lane>>4)+reg
#pragma unroll
    for (int mt = 0; mt < 2; ++mt) {
#pragma unroll
        for (int nt = 0; nt < 4; ++nt) {
            int col = n0 + nt * 16 + lr;
            float bv_ = bias[col];
            int row0 = m0 + w * 32 + mt * 16 + g * 4;
#pragma unroll
            for (int r = 0; r < 4; ++r)
                out[(size_t)(row0 + r) * CDIM + col] = f2bf(acc[mt][nt][r] + bv_);
        }
    }
}

// ---------------- fused windowed cross-attention ----------------
// grid: 512 blocks = (b*8+h)*16 + qtile ; block 256 = 4 waves, wave owns 16 queries.
// Per patch p: S^T = mfma(K, Q) (swapped) -> softmax over s in 2 shfl_xor ->
// P^T feeds PV mfma B-operand directly (K=32, upper 16 zero-padded); A = V^T from LDS.
__global__ __launch_bounds__(256, 2) void attn_k(
    const short* __restrict__ q_bf, const short* __restrict__ k_bf,
    const short* __restrict__ v_bf, float* __restrict__ out) {
    __shared__ __attribute__((aligned(16))) short k_lds[S2 * 64];       // [s][64] XOR-swizzled
    __shared__ __attribute__((aligned(16))) short vT_lds[64 * S2];      // [d][s]
    const int blk = blockIdx.x;
    const int qtile = blk & 15;
    const int bh = blk >> 4;
    const int b = bh >> 3, h = bh & 7;
    const int t = threadIdx.x, w = t >> 6, lane = t & 63;
    const int lr = lane & 15, g = lane >> 4;
    const int l_loc = qtile * 64 + w * 16 + lr;   // query index (0..1023)

    // Q fragments (persist): B-operand, col = lr, k-slot(g,i) = j*32 + g*8 + i
    bf16x8 qfr[2];
    {
        const short* qrow = q_bf + (size_t)(b * NPX + l_loc) * CDIM + h * HD;
        qfr[0] = *(const bf16x8*)(qrow + g * 8);
        qfr[1] = *(const bf16x8*)(qrow + 32 + g * 8);
    }
    float* outbh = out + (size_t)bh * PS * NPX * HD;

    for (int p = 0; p < PS; ++p) {
        {   // stage K patch [16][64] (swizzled) and V^T [64][16]
            int s = t >> 4;
            int c4 = (t & 15) * 4;
            int py = p >> 3, px = p & 7;
            int n = (py * 4 + (s >> 2)) * 32 + px * 4 + (s & 3);
            const short* krow = k_bf + (size_t)(b * NPX + n) * CDIM + h * HD;
            const short* vrow = v_bf + (size_t)(b * NPX + n) * CDIM + h * HD;
            int widx = (s * 64 + c4) ^ ((s & 7) << 3);
            *(short4*)(k_lds + widx) = *(const short4*)(krow + c4);
            short4 vv = *(const short4*)(vrow + c4);
            vT_lds[(c4 + 0) * S2 + s] = vv.x;
            vT_lds[(c4 + 1) * S2 + s] = vv.y;
            vT_lds[(c4 + 2) * S2 + s] = vv.z;
            vT_lds[(c4 + 3) * S2 + s] = vv.w;
        }
        __syncthreads();
        // K A-frags: row = s = lr, k-slot = j*32 + g*8 + i  (same convention as Q)
        bf16x8 kfr0 = *(const bf16x8*)(k_lds + ((lr * 64 + g * 8) ^ ((lr & 7) << 3)));
        bf16x8 kfr1 = *(const bf16x8*)(k_lds + ((lr * 64 + 32 + g * 8) ^ ((lr & 7) << 3)));
        // V^T A-frags: row = d = dt*16+lr, k-slot(g, i<4) = s = 4g+i
        bf16x4 vfr4[4];
#pragma unroll
        for (int dt = 0; dt < 4; ++dt)
            vfr4[dt] = *(const bf16x4*)(vT_lds + (dt * 16 + lr) * S2 + g * 4);

        f32x4 s_acc = {};
        s_acc = __builtin_amdgcn_mfma_f32_16x16x32_bf16(kfr0, qfr[0], s_acc, 0, 0, 0);
        s_acc = __builtin_amdgcn_mfma_f32_16x16x32_bf16(kfr1, qfr[1], s_acc, 0, 0, 0);
        // lane holds S^T[s = 4g+reg][l = lr] ; softmax over all 16 s
        float sv[4];
        float m = -1e30f;
#pragma unroll
        for (int r = 0; r < 4; ++r) { sv[r] = s_acc[r] * 0.125f; m = fmaxf(m, sv[r]); }
        m = fmaxf(m, __shfl_xor(m, 16));
        m = fmaxf(m, __shfl_xor(m, 32));
        float pv[4]; float sum = 0.f;
#pragma unroll
        for (int r = 0; r < 4; ++r) { pv[r] = __expf(sv[r] - m); sum += pv[r]; }
        sum += __shfl_xor(sum, 16);
        sum += __shfl_xor(sum, 32);
        float rs = 1.f / sum;
        bf16x8 pfr = { f2bf(pv[0] * rs), f2bf(pv[1] * rs), f2bf(pv[2] * rs), f2bf(pv[3] * rs),
                       0, 0, 0, 0 };
        // PV: out^T[d][l] = sum_s V[s][d] * P^T[s][l]
        f32x4 oacc[4];
#pragma unroll
        for (int dt = 0; dt < 4; ++dt) {
            bf16x8 vfr = { vfr4[dt][0], vfr4[dt][1], vfr4[dt][2], vfr4[dt][3], 0, 0, 0, 0 };
            f32x4 zero = {};
            oacc[dt] = __builtin_amdgcn_mfma_f32_16x16x32_bf16(vfr, pfr, zero, 0, 0, 0);
        }
        // store: lane holds out[l=l_loc][d = dt*16 + 4g + r]
        float* op = outbh + ((size_t)p * NPX + l_loc) * HD;
#pragma unroll
        for (int dt = 0; dt < 4; ++dt)
            *(float4*)(op + dt * 16 + g * 4) = *(float4*)&oacc[dt];
        __syncthreads();
    }
}

extern "C" void kernel_launch(void* const* d_in, const int* in_sizes, int n_in,
                              void* d_out, int out_size, void* d_ws, size_t ws_size,
                              hipStream_t stream) {
    const float* x_s = (const float*)d_in[0];
    const float* x_l = (const float*)d_in[1];
    const float* Wq  = (const float*)d_in[2];
    const float* bq  = (const float*)d_in[3];
    const float* Wk  = (const float*)d_in[4];
    const float* bk  = (const float*)d_in[5];
    const float* Wv  = (const float*)d_in[6];
    const float* bv  = (const float*)d_in[7];
    float* out = (float*)d_out;
    char* ws = (char*)d_ws;

    short* xl_bf = (short*)(ws);                    // 4 MiB
    short* xs_bf = (short*)(ws + 4194304);          // 4 MiB
    short* WT    = (short*)(ws + 8388608);          // 1.5 MiB
    short* qkv   = (short*)(ws + 9961472);          // 12 MiB  (q,k,v each 2097152 shorts)
    short* q_bf = qkv;
    short* k_bf = qkv + 2097152;
    short* v_bf = qkv + 4194304;

    convert_k<<<3072, 256, 0, stream>>>(x_s, x_l, Wq, Wk, Wv, xl_bf, xs_bf, WT);
    proj_gemm<<<dim3(32, 8, 3), 256, 0, stream>>>(xl_bf, xs_bf, WT, bq, bk, bv, qkv);
    attn_k<<<512, 256, 0, stream>>>(q_bf, k_bf, v_bf, out);
}